// Round 8
// baseline (282.241 us; speedup 1.0000x reference)
//
#include <hip/hip_runtime.h>

#define NB 8192
#define NT 365
#define NF 5
#define NH 10
#define NHH 5   // NH/2
#define NG 40   // 4*NH

// Quad broadcast via DPP quad_perm (within each aligned 4-lane quad).
template<int CTRL>
__device__ __forceinline__ float qb(float v) {
    return __int_as_float(
        __builtin_amdgcn_mov_dpp(__float_as_int(v), CTRL, 0xF, 0xF, true));
}
// Exchange with lane^4 (across the two quads of an 8-group).
__device__ __forceinline__ float xswap4(float v) {
    return __int_as_float(__builtin_amdgcn_ds_swizzle(__float_as_int(v), 0x101F));
}
// Exchange with lane^8 (across the two reduction-split copies of a 16-group).
__device__ __forceinline__ float xswap8(float v) {
    return __int_as_float(__builtin_amdgcn_ds_swizzle(__float_as_int(v), 0x201F));
}

// 16 lanes per batch element: lane = (rs<<3)|(half<<2)|lq.
//   lq   : gate block f,i,o,g (jnp.split order)
//   half : output hidden columns [half*5, half*5+5)
//   rs   : reduction split -- rs=0 sums x-features {0,1,2} + h[0..5) (+bias),
//          rs=1 sums x-features {3,4} + h[5..10). One xor-8 swizzle+add
//          combines the partials (commutative add -> both copies identical).
// Downstream (activation, quad DPP gate broadcast, c/h update) is replicated
// across rs; h-halves are exchanged with xor-4 so each lane keeps the h-half
// its rs needs. Grid = NB*16 threads = 2048 waves = 2 waves/SIMD.
__global__ __launch_bounds__(256)
void lstm_fused16(const float* __restrict__ x,
                  const float* __restrict__ w_ih,
                  const float* __restrict__ w_hh,
                  const float* __restrict__ bias,
                  const float* __restrict__ fc_w,
                  const float* __restrict__ fc_b,
                  float* __restrict__ out)
{
    const int tid  = blockIdx.x * 256 + threadIdx.x;
    const int lq   = tid & 3;
    const int half = (tid >> 2) & 1;
    const int rs   = (tid >> 3) & 1;
    const int b    = tid >> 4;

    float* h_out = out + NB;
    float* c_out = h_out + (size_t)NB * NT * NH;

    const int col0 = lq * NH + half * NHH;
    const int f0 = rs ? 3 : 0;      // this lane's x-feature window (3 wide, padded)
    const int j0 = rs ? NHH : 0;    // this lane's h-term window

    float wih[3][NHH], whh[NHH][NHH], bs[NHH];
    #pragma unroll
    for (int fi = 0; fi < 3; ++fi) {
        const int f = (f0 + fi < NF) ? (f0 + fi) : (NF - 1);
        const bool dead = (rs && fi == 2);   // rs=1 pads its 3rd feature with w=0
        #pragma unroll
        for (int k = 0; k < NHH; ++k)
            wih[fi][k] = dead ? 0.f : w_ih[f * NG + col0 + k];
    }
    #pragma unroll
    for (int jj = 0; jj < NHH; ++jj)
        #pragma unroll
        for (int k = 0; k < NHH; ++k)
            whh[jj][k] = w_hh[(j0 + jj) * NG + col0 + k];
    #pragma unroll
    for (int k = 0; k < NHH; ++k) bs[k] = rs ? 0.f : bias[col0 + k];

    float hl[NHH], c[NHH], hh[NHH], ho[NHH];
    #pragma unroll
    for (int k = 0; k < NHH; ++k) { hl[k] = 0.f; c[k] = 0.f; hh[k] = 0.f; ho[k] = 0.f; }

    const float sc  = (lq == 3) ? -2.0f : -1.0f;   // gate g: tanh = 2*sigmoid(2x)-1
    const bool  isg = (lq == 3);
    const bool  keep_own = (half == rs);           // own hh-half == needed h-half?
    const bool  dostore  = (rs == 0);

    const float* xp = x + (size_t)b * NT * NF;
    float* hb = h_out + (size_t)b * NT * NH + half * NHH;
    float* cb = c_out + (size_t)b * NT * NH + half * NHH;
    float* sb = ((lq < 2) ? hb : cb) + ((lq & 1) ? 3 : 0);

    float xv[3];
    #pragma unroll
    for (int fi = 0; fi < 3; ++fi) {
        const int f = (f0 + fi < NF) ? (f0 + fi) : (NF - 1);
        xv[fi] = xp[f];
    }

    for (int t = 0; t < NT; ++t) {
        // prefetch next timestep's x window (clamped)
        float xn[3];
        const float* xnp = xp + (size_t)((t + 1 < NT) ? (t + 1) : t) * NF;
        #pragma unroll
        for (int fi = 0; fi < 3; ++fi) {
            const int f = (f0 + fi < NF) ? (f0 + fi) : (NF - 1);
            xn[fi] = xnp[f];
        }

        // ---- 5 partial gate dots (this lane's reduction slice) ----
        float r[NHH];
        #pragma unroll
        for (int k = 0; k < NHH; ++k) {
            float a = bs[k];
            #pragma unroll
            for (int fi = 0; fi < 3; ++fi) a = fmaf(xv[fi], wih[fi][k], a);
            #pragma unroll
            for (int jj = 0; jj < NHH; ++jj) a = fmaf(hl[jj], whh[jj][k], a);
            r[k] = a;
        }
        // ---- combine the two reduction halves (xor-8), then activate ----
        float y[NHH];
        #pragma unroll
        for (int k = 0; k < NHH; ++k) {
            float rf = r[k] + xswap8(r[k]);
            float e = __expf(sc * rf);
            float s = __builtin_amdgcn_rcpf(1.0f + e);
            y[k] = isg ? fmaf(2.0f, s, -1.0f) : s;
        }

        // ---- quad gate broadcast + replicated c,h update ----
        #pragma unroll
        for (int k = 0; k < NHH; ++k) {
            float yf = qb<0x00>(y[k]);   // sigmoid(f)
            float yi = qb<0x55>(y[k]);   // sigmoid(i)
            float yo = qb<0xAA>(y[k]);   // sigmoid(o)
            float tg = qb<0xFF>(y[k]);   // tanh(g)
            float cn = fmaf(yf, c[k], yi * tg);
            c[k] = cn;
            float e2 = __expf(-2.0f * cn);
            float th = fmaf(2.0f, __builtin_amdgcn_rcpf(1.0f + e2), -1.0f);
            hh[k] = yo * th;
        }

        // ---- keep the h-half this lane's reduction slice needs ----
        #pragma unroll
        for (int k = 0; k < NHH; ++k) ho[k] = xswap4(hh[k]);
        #pragma unroll
        for (int k = 0; k < NHH; ++k) hl[k] = keep_own ? hh[k] : ho[k];

        // ---- store (rs=0 lanes only; same split as the 8-lane kernel) ----
        if (dostore) {
            float a0 = (lq < 2) ? hh[0] : c[0];
            float a1 = (lq < 2) ? hh[1] : c[1];
            float a2 = (lq < 2) ? hh[2] : c[2];
            float a3 = (lq < 2) ? hh[3] : c[3];
            float a4 = (lq < 2) ? hh[4] : c[4];
            sb[0] = (lq & 1) ? a3 : a0;
            sb[1] = (lq & 1) ? a4 : a1;
            if (!(lq & 1)) sb[2] = a2;
        }
        sb += NH;

        #pragma unroll
        for (int fi = 0; fi < 3; ++fi) xv[fi] = xn[fi];
    }

    // ---- fc head: lane 0 of each 16-group. Its hh = h[0..4] (half=0),
    //      ho = partner's hh = h[5..9] (from the final step's xswap4). ----
    if ((tid & 15) == 0) {
        float acc = fc_b[0];
        #pragma unroll
        for (int k = 0; k < NHH; ++k) acc = fmaf(hh[k], fc_w[k], acc);
        #pragma unroll
        for (int k = 0; k < NHH; ++k) acc = fmaf(ho[k], fc_w[k + NHH], acc);
        out[b] = acc;
    }
}

extern "C" void kernel_launch(void* const* d_in, const int* in_sizes, int n_in,
                              void* d_out, int out_size, void* d_ws, size_t ws_size,
                              hipStream_t stream) {
    const float* x    = (const float*)d_in[0];
    const float* wih  = (const float*)d_in[1];
    const float* whh  = (const float*)d_in[2];
    const float* bias = (const float*)d_in[3];
    const float* fcw  = (const float*)d_in[4];
    const float* fcb  = (const float*)d_in[5];
    float* out = (float*)d_out;

    const int threads = NB * 16;         // 16 lanes per batch element
    const int block = 256;
    lstm_fused16<<<threads / block, block, 0, stream>>>(x, wih, whh, bias, fcw, fcb, out);
}

// Round 9
// 259.095 us; speedup vs baseline: 1.0893x; 1.0893x over previous
//
#include <hip/hip_runtime.h>

#define NB 8192
#define NT 365
#define NF 5
#define NH 10
#define NHH 5   // NH/2
#define NG 40   // 4*NH

// Quad broadcast via DPP quad_perm (within each aligned 4-lane quad).
template<int CTRL>
__device__ __forceinline__ float qb(float v) {
    return __int_as_float(
        __builtin_amdgcn_mov_dpp(__float_as_int(v), CTRL, 0xF, 0xF, true));
}
// Exchange with lane^4 (across the two quads of an 8-group).
__device__ __forceinline__ float xswap4(float v) {
    return __int_as_float(__builtin_amdgcn_ds_swizzle(__float_as_int(v), 0x101F));
}

// 8 lanes per batch element: lane = (half<<2)|lq.
//   lq   = gate block f,i,o,g (jnp.split order); half = hidden cols [half*5,+5)
// Weights live in VGPRs, forced resident by __launch_bounds__(256,1)
// (grid gives only 1 wave/SIMD anyway, so no occupancy to lose).
// whh rows are PERMUTED at load (own half first, other half second) so the
// recurrent dot consumes (hh, ho) directly -- no h reassembly selects.
// g-gate weights/bias pre-scaled by 2 so all lanes run exp(-r) uniformly
// (tanh(x) = 2*sigmoid(2x)-1).
// x-projection xa = b + x_t.W_ih is computed one step AHEAD (independent
// work that fills the update-chain stall slots).
__global__ __launch_bounds__(256, 1)
void lstm_fused8r(const float* __restrict__ x,
                  const float* __restrict__ w_ih,
                  const float* __restrict__ w_hh,
                  const float* __restrict__ bias,
                  const float* __restrict__ fc_w,
                  const float* __restrict__ fc_b,
                  float* __restrict__ out)
{
    const int tid  = blockIdx.x * 256 + threadIdx.x;
    const int lq   = tid & 3;          // gate
    const int half = (tid >> 2) & 1;   // hidden half
    const int b    = tid >> 3;         // batch element

    float* h_out = out + NB;
    float* c_out = h_out + (size_t)NB * NT * NH;

    const int col0 = lq * NH + half * NHH;
    const float gs = (lq == 3) ? 2.0f : 1.0f;   // pre-scale for tanh-as-sigmoid
    const bool isg = (lq == 3);

    // ---- resident weights: wih 25, whh 50 (row-permuted), bias 5 ----
    float wih[NF][NHH], whh_own[NHH][NHH], whh_oth[NHH][NHH], bs[NHH];
    #pragma unroll
    for (int f = 0; f < NF; ++f)
        #pragma unroll
        for (int k = 0; k < NHH; ++k) wih[f][k] = w_ih[f * NG + col0 + k] * gs;
    #pragma unroll
    for (int jj = 0; jj < NHH; ++jj)
        #pragma unroll
        for (int k = 0; k < NHH; ++k) {
            whh_own[jj][k] = w_hh[(half * NHH + jj) * NG + col0 + k] * gs;
            whh_oth[jj][k] = w_hh[((1 - half) * NHH + jj) * NG + col0 + k] * gs;
        }
    #pragma unroll
    for (int k = 0; k < NHH; ++k) bs[k] = bias[col0 + k] * gs;

    float hh[NHH], ho[NHH], c[NHH];
    #pragma unroll
    for (int k = 0; k < NHH; ++k) { hh[k] = 0.f; ho[k] = 0.f; c[k] = 0.f; }

    const float* xp = x + (size_t)b * NT * NF;
    float* hb = h_out + (size_t)b * NT * NH + half * NHH;
    float* cb = c_out + (size_t)b * NT * NH + half * NHH;
    float* sb = ((lq < 2) ? hb : cb) + ((lq & 1) ? 3 : 0);

    // xa = bias + x_0 . W_ih  (one step ahead of the loop)
    float xa[NHH];
    {
        float x0[NF];
        #pragma unroll
        for (int f = 0; f < NF; ++f) x0[f] = xp[f];
        #pragma unroll
        for (int k = 0; k < NHH; ++k) {
            float a = bs[k];
            #pragma unroll
            for (int f = 0; f < NF; ++f) a = fmaf(x0[f], wih[f][k], a);
            xa[k] = a;
        }
    }

    for (int t = 0; t < NT; ++t) {
        // issue next-step x loads early (consumed at loop bottom)
        float xn[NF];
        const float* xnp = xp + (size_t)((t + 1 < NT) ? (t + 1) : t) * NF;
        #pragma unroll
        for (int f = 0; f < NF; ++f) xn[f] = xnp[f];

        // ---- recurrent dot + activation: r = xa + hh.Wown + ho.Woth ----
        float y[NHH];
        #pragma unroll
        for (int k = 0; k < NHH; ++k) {
            float a = xa[k];
            #pragma unroll
            for (int jj = 0; jj < NHH; ++jj) a = fmaf(hh[jj], whh_own[jj][k], a);
            #pragma unroll
            for (int jj = 0; jj < NHH; ++jj) a = fmaf(ho[jj], whh_oth[jj][k], a);
            float e = __expf(-a);                       // uniform: g pre-scaled
            float s = __builtin_amdgcn_rcpf(1.0f + e);
            y[k] = isg ? fmaf(2.0f, s, -1.0f) : s;
        }

        // ---- quad gate broadcast + own-half c,h update ----
        #pragma unroll
        for (int k = 0; k < NHH; ++k) {
            float yf = qb<0x00>(y[k]);   // sigmoid(f)
            float yi = qb<0x55>(y[k]);   // sigmoid(i)
            float yo = qb<0xAA>(y[k]);   // sigmoid(o)
            float tg = qb<0xFF>(y[k]);   // tanh(g)
            float cn = fmaf(yf, c[k], yi * tg);
            c[k] = cn;
            float e2 = __expf(-2.0f * cn);
            float th = fmaf(2.0f, __builtin_amdgcn_rcpf(1.0f + e2), -1.0f);
            hh[k] = yo * th;
        }

        // ---- fetch other half of h (weight permutation needs no selects) ----
        #pragma unroll
        for (int k = 0; k < NHH; ++k) ho[k] = xswap4(hh[k]);

        // ---- store this lane's slice of (h,c) ----
        {
            float a0 = (lq < 2) ? hh[0] : c[0];
            float a1 = (lq < 2) ? hh[1] : c[1];
            float a2 = (lq < 2) ? hh[2] : c[2];
            float a3 = (lq < 2) ? hh[3] : c[3];
            float a4 = (lq < 2) ? hh[4] : c[4];
            sb[0] = (lq & 1) ? a3 : a0;
            sb[1] = (lq & 1) ? a4 : a1;
            if (!(lq & 1)) sb[2] = a2;
            sb += NH;
        }

        // ---- next step's x-projection (independent, fills stalls) ----
        #pragma unroll
        for (int k = 0; k < NHH; ++k) {
            float a = bs[k];
            #pragma unroll
            for (int f = 0; f < NF; ++f) a = fmaf(xn[f], wih[f][k], a);
            xa[k] = a;
        }
    }

    // ---- fc head: lane (half=0,lq=0) holds h[0..4]=hh, h[5..9]=ho ----
    if ((tid & 7) == 0) {
        float acc = fc_b[0];
        #pragma unroll
        for (int k = 0; k < NHH; ++k) acc = fmaf(hh[k], fc_w[k], acc);
        #pragma unroll
        for (int k = 0; k < NHH; ++k) acc = fmaf(ho[k], fc_w[k + NHH], acc);
        out[b] = acc;
    }
}

extern "C" void kernel_launch(void* const* d_in, const int* in_sizes, int n_in,
                              void* d_out, int out_size, void* d_ws, size_t ws_size,
                              hipStream_t stream) {
    const float* x    = (const float*)d_in[0];
    const float* wih  = (const float*)d_in[1];
    const float* whh  = (const float*)d_in[2];
    const float* bias = (const float*)d_in[3];
    const float* fcw  = (const float*)d_in[4];
    const float* fcb  = (const float*)d_in[5];
    float* out = (float*)d_out;

    const int threads = NB * 8;          // 8 lanes per batch element
    const int block = 256;
    lstm_fused8r<<<threads / block, block, 0, stream>>>(x, wih, whh, bias, fcw, fcb, out);
}

// Round 10
// 256.307 us; speedup vs baseline: 1.1012x; 1.0109x over previous
//
#include <hip/hip_runtime.h>

#define NB 8192
#define NT 365
#define NF 5
#define NH 10
#define NHH 5   // NH/2
#define NG 40   // 4*NH

// Quad broadcast via DPP quad_perm (within each aligned 4-lane quad).
template<int CTRL>
__device__ __forceinline__ float qb(float v) {
    return __int_as_float(
        __builtin_amdgcn_mov_dpp(__float_as_int(v), CTRL, 0xF, 0xF, true));
}
// Exchange with lane^4 (across the two quads of an 8-group).
__device__ __forceinline__ float xswap4(float v) {
    return __int_as_float(__builtin_amdgcn_ds_swizzle(__float_as_int(v), 0x101F));
}
// Pin a value into a VGPR: opaque asm output cannot be rematerialized, so the
// register allocator must keep it live across the t-loop (r9 showed the
// compiler otherwise re-loads weights from cache every timestep: VGPR=68 for
// 80+ live floats).
__device__ __forceinline__ void pin(float& v) { asm volatile("" : "+v"(v)); }

// 8 lanes per batch element: lane = (half<<2)|lq.
//   lq   = gate block f,i,o,g (jnp.split order); half = hidden cols [half*5,+5)
// whh rows PERMUTED at load (own half first) so the recurrent dot consumes
// (hh, ho) directly. g-gate weights/bias pre-scaled by 2 -> uniform exp(-r)
// path (tanh(x) = 2*sigmoid(2x)-1). x-projection computed one step ahead.
__global__ __launch_bounds__(256, 1)
void lstm_fused8p(const float* __restrict__ x,
                  const float* __restrict__ w_ih,
                  const float* __restrict__ w_hh,
                  const float* __restrict__ bias,
                  const float* __restrict__ fc_w,
                  const float* __restrict__ fc_b,
                  float* __restrict__ out)
{
    const int tid  = blockIdx.x * 256 + threadIdx.x;
    const int lq   = tid & 3;          // gate
    const int half = (tid >> 2) & 1;   // hidden half
    const int b    = tid >> 3;         // batch element

    float* h_out = out + NB;
    float* c_out = h_out + (size_t)NB * NT * NH;

    const int col0 = lq * NH + half * NHH;
    const float gs = (lq == 3) ? 2.0f : 1.0f;   // pre-scale for tanh-as-sigmoid
    const bool isg = (lq == 3);

    // ---- load weights, then PIN into VGPRs (80 registers) ----
    float wih[NF][NHH], whh_own[NHH][NHH], whh_oth[NHH][NHH], bs[NHH];
    #pragma unroll
    for (int f = 0; f < NF; ++f)
        #pragma unroll
        for (int k = 0; k < NHH; ++k) wih[f][k] = w_ih[f * NG + col0 + k] * gs;
    #pragma unroll
    for (int jj = 0; jj < NHH; ++jj)
        #pragma unroll
        for (int k = 0; k < NHH; ++k) {
            whh_own[jj][k] = w_hh[(half * NHH + jj) * NG + col0 + k] * gs;
            whh_oth[jj][k] = w_hh[((1 - half) * NHH + jj) * NG + col0 + k] * gs;
        }
    #pragma unroll
    for (int k = 0; k < NHH; ++k) bs[k] = bias[col0 + k] * gs;

    #pragma unroll
    for (int f = 0; f < NF; ++f)
        #pragma unroll
        for (int k = 0; k < NHH; ++k) pin(wih[f][k]);
    #pragma unroll
    for (int jj = 0; jj < NHH; ++jj)
        #pragma unroll
        for (int k = 0; k < NHH; ++k) { pin(whh_own[jj][k]); pin(whh_oth[jj][k]); }
    #pragma unroll
    for (int k = 0; k < NHH; ++k) pin(bs[k]);

    float hh[NHH], ho[NHH], c[NHH];
    #pragma unroll
    for (int k = 0; k < NHH; ++k) { hh[k] = 0.f; ho[k] = 0.f; c[k] = 0.f; }

    const float* xp = x + (size_t)b * NT * NF;
    float* hb = h_out + (size_t)b * NT * NH + half * NHH;
    float* cb = c_out + (size_t)b * NT * NH + half * NHH;
    float* sb = ((lq < 2) ? hb : cb) + ((lq & 1) ? 3 : 0);

    // xa = bias + x_0 . W_ih  (one step ahead of the loop)
    float xa[NHH];
    {
        float x0[NF];
        #pragma unroll
        for (int f = 0; f < NF; ++f) x0[f] = xp[f];
        #pragma unroll
        for (int k = 0; k < NHH; ++k) {
            float a = bs[k];
            #pragma unroll
            for (int f = 0; f < NF; ++f) a = fmaf(x0[f], wih[f][k], a);
            xa[k] = a;
        }
    }

    for (int t = 0; t < NT; ++t) {
        // issue next-step x loads early (consumed at loop bottom)
        float xn[NF];
        const float* xnp = xp + (size_t)((t + 1 < NT) ? (t + 1) : t) * NF;
        #pragma unroll
        for (int f = 0; f < NF; ++f) xn[f] = xnp[f];

        // ---- recurrent dot + activation: r = xa + hh.Wown + ho.Woth ----
        float y[NHH];
        #pragma unroll
        for (int k = 0; k < NHH; ++k) {
            float a = xa[k];
            #pragma unroll
            for (int jj = 0; jj < NHH; ++jj) a = fmaf(hh[jj], whh_own[jj][k], a);
            #pragma unroll
            for (int jj = 0; jj < NHH; ++jj) a = fmaf(ho[jj], whh_oth[jj][k], a);
            float e = __expf(-a);                       // uniform: g pre-scaled
            float s = __builtin_amdgcn_rcpf(1.0f + e);
            y[k] = isg ? fmaf(2.0f, s, -1.0f) : s;
        }

        // ---- quad gate broadcast + own-half c,h update ----
        #pragma unroll
        for (int k = 0; k < NHH; ++k) {
            float yf = qb<0x00>(y[k]);   // sigmoid(f)
            float yi = qb<0x55>(y[k]);   // sigmoid(i)
            float yo = qb<0xAA>(y[k]);   // sigmoid(o)
            float tg = qb<0xFF>(y[k]);   // tanh(g)
            float cn = fmaf(yf, c[k], yi * tg);
            c[k] = cn;
            float e2 = __expf(-2.0f * cn);
            float th = fmaf(2.0f, __builtin_amdgcn_rcpf(1.0f + e2), -1.0f);
            hh[k] = yo * th;
        }

        // ---- fetch other half of h (weight permutation needs no selects) ----
        #pragma unroll
        for (int k = 0; k < NHH; ++k) ho[k] = xswap4(hh[k]);

        // ---- store this lane's slice of (h,c) ----
        {
            float a0 = (lq < 2) ? hh[0] : c[0];
            float a1 = (lq < 2) ? hh[1] : c[1];
            float a2 = (lq < 2) ? hh[2] : c[2];
            float a3 = (lq < 2) ? hh[3] : c[3];
            float a4 = (lq < 2) ? hh[4] : c[4];
            sb[0] = (lq & 1) ? a3 : a0;
            sb[1] = (lq & 1) ? a4 : a1;
            if (!(lq & 1)) sb[2] = a2;
            sb += NH;
        }

        // ---- next step's x-projection (independent, fills stalls) ----
        #pragma unroll
        for (int k = 0; k < NHH; ++k) {
            float a = bs[k];
            #pragma unroll
            for (int f = 0; f < NF; ++f) a = fmaf(xn[f], wih[f][k], a);
            xa[k] = a;
        }
    }

    // ---- fc head: lane (half=0,lq=0) holds h[0..4]=hh, h[5..9]=ho ----
    if ((tid & 7) == 0) {
        float acc = fc_b[0];
        #pragma unroll
        for (int k = 0; k < NHH; ++k) acc = fmaf(hh[k], fc_w[k], acc);
        #pragma unroll
        for (int k = 0; k < NHH; ++k) acc = fmaf(ho[k], fc_w[k + NHH], acc);
        out[b] = acc;
    }
}

extern "C" void kernel_launch(void* const* d_in, const int* in_sizes, int n_in,
                              void* d_out, int out_size, void* d_ws, size_t ws_size,
                              hipStream_t stream) {
    const float* x    = (const float*)d_in[0];
    const float* wih  = (const float*)d_in[1];
    const float* whh  = (const float*)d_in[2];
    const float* bias = (const float*)d_in[3];
    const float* fcw  = (const float*)d_in[4];
    const float* fcb  = (const float*)d_in[5];
    float* out = (float*)d_out;

    const int threads = NB * 8;          // 8 lanes per batch element
    const int block = 256;
    lstm_fused8p<<<threads / block, block, 0, stream>>>(x, wih, whh, bias, fcw, fcb, out);
}